// Round 6
// baseline (369.379 us; speedup 1.0000x reference)
//
#include <hip/hip_runtime.h>

// Problem dims
#define MB_T 16384   // B*T
#define DD   512     // model hidden
#define CC   4096    // context entries
#define AA   512     // attn dim
#define PP   512     // out dim

typedef __attribute__((ext_vector_type(4))) float f32x4;
typedef __attribute__((ext_vector_type(8))) short short8;

#define MFMA16(a, b, c) __builtin_amdgcn_mfma_f32_16x16x32_bf16((a), (b), (c), 0, 0, 0)

__device__ __forceinline__ unsigned short f2bf(float f) {
  union { float f; unsigned int u; } cv; cv.f = f;
  unsigned int u = cv.u;
  return (unsigned short)((u + 0x7FFFu + ((u >> 16) & 1u)) >> 16);
}
__device__ __forceinline__ float bf2f(unsigned short u) {
  union { unsigned int i; float f; } c; c.i = (unsigned int)u << 16; return c.f;
}

// async global->LDS, 16B per lane; lds dest is wave-uniform base (+lane*16 by HW)
__device__ __forceinline__ void gload16(const unsigned short* g, unsigned short* l) {
  __builtin_amdgcn_global_load_lds(
      (const __attribute__((address_space(1))) unsigned int*)g,
      (__attribute__((address_space(3))) unsigned int*)l, 16, 0, 0);
}

// ---------------- cast fp32 -> bf16, x4 vectorized ----------------
__global__ void cast_bf16_kernel(const float* __restrict__ in,
                                 unsigned short* __restrict__ out, int n4) {
  int i = blockIdx.x * blockDim.x + threadIdx.x;
  int stride = gridDim.x * blockDim.x;
  for (; i < n4; i += stride) {
    float4 v = reinterpret_cast<const float4*>(in)[i];
    ushort4 o;
    o.x = f2bf(v.x); o.y = f2bf(v.y); o.z = f2bf(v.z); o.w = f2bf(v.w);
    reinterpret_cast<ushort4*>(out)[i] = o;
  }
}

// three casts in one launch (blockIdx.y selects array)
__global__ void cast3_kernel(const float* __restrict__ i0, const float* __restrict__ i1,
                             const float* __restrict__ i2, unsigned short* __restrict__ o0,
                             unsigned short* __restrict__ o1, unsigned short* __restrict__ o2,
                             int n4) {
  const float* in = blockIdx.y == 0 ? i0 : blockIdx.y == 1 ? i1 : i2;
  unsigned short* out = blockIdx.y == 0 ? o0 : blockIdx.y == 1 ? o1 : o2;
  int i = blockIdx.x * blockDim.x + threadIdx.x;
  if (i < n4) {
    float4 v = reinterpret_cast<const float4*>(in)[i];
    ushort4 o;
    o.x = f2bf(v.x); o.y = f2bf(v.y); o.z = f2bf(v.z); o.w = f2bf(v.w);
    reinterpret_cast<ushort4*>(out)[i] = o;
  }
}

// ---------------- W [rows][cols] f32 -> WT [cols][rows] bf16 ----------------
__global__ __launch_bounds__(256) void transpose_cast_kernel(
    const float* __restrict__ W, unsigned short* __restrict__ WT, int rows, int cols) {
  __shared__ float t_s[32][33];
  int bi = blockIdx.y * 32, bj = blockIdx.x * 32;
  int r = threadIdx.x >> 3, c4 = (threadIdx.x & 7) * 4;
  float4 v = *reinterpret_cast<const float4*>(W + (size_t)(bi + r) * cols + bj + c4);
  t_s[r][c4 + 0] = v.x; t_s[r][c4 + 1] = v.y;
  t_s[r][c4 + 2] = v.z; t_s[r][c4 + 3] = v.w;
  __syncthreads();
  ushort4 o;
  o.x = f2bf(t_s[c4 + 0][r]);
  o.y = f2bf(t_s[c4 + 1][r]);
  o.z = f2bf(t_s[c4 + 2][r]);
  o.w = f2bf(t_s[c4 + 3][r]);
  *reinterpret_cast<ushort4*>(WT + (size_t)(bj + r) * rows + bi + c4) = o;
}

// ---------------- out[r] = scale * dot(mat[r,0:512], vec) ----------------
__device__ __forceinline__ void rowdot_body(const unsigned short* mat, const float* vec,
                                            float* outv, float scale) {
  const int lane = threadIdx.x & 63, wid = threadIdx.x >> 6;
  const int row = blockIdx.x * 4 + wid;
  const unsigned short* kr = mat + (size_t)row * 512 + lane * 8;
  float s = 0.f;
  ushort4 a = *reinterpret_cast<const ushort4*>(kr);
  ushort4 b = *reinterpret_cast<const ushort4*>(kr + 4);
  const float* bqp = vec + lane * 8;
  s += bf2f(a.x) * bqp[0]; s += bf2f(a.y) * bqp[1];
  s += bf2f(a.z) * bqp[2]; s += bf2f(a.w) * bqp[3];
  s += bf2f(b.x) * bqp[4]; s += bf2f(b.y) * bqp[5];
  s += bf2f(b.z) * bqp[6]; s += bf2f(b.w) * bqp[7];
#pragma unroll
  for (int d = 1; d < 64; d <<= 1) s += __shfl_xor(s, d);
  if (lane == 0) outv[row] = s * scale;
}

__global__ __launch_bounds__(256) void rowdot_kernel(
    const unsigned short* __restrict__ mat, const float* __restrict__ vec,
    float* __restrict__ outv, float scale) {
  rowdot_body(mat, vec, outv, scale);
}

// three independent 512-row rowdots in one launch
__global__ __launch_bounds__(256) void rowdot3_kernel(
    const unsigned short* m0, const float* v0, float* o0, float s0,
    const unsigned short* m1, const float* v1, float* o1, float s1,
    const unsigned short* m2, const float* v2, float* o2, float s2) {
  if (blockIdx.y == 0) rowdot_body(m0, v0, o0, s0);
  else if (blockIdx.y == 1) rowdot_body(m1, v1, o1, s1);
  else rowdot_body(m2, v2, o2, s2);
}

// ---------------- lsum[m] = sum_j lsp[m*64+j] ----------------
__global__ __launch_bounds__(256) void reduce_lsum_kernel(
    const float* __restrict__ lsp, float* __restrict__ lsum) {
  int m = blockIdx.x * blockDim.x + threadIdx.x;
  const float4* p = reinterpret_cast<const float4*>(lsp + (size_t)m * 64);
  float s = 0.f;
#pragma unroll
  for (int j = 0; j < 16; ++j) { float4 v = p[j]; s += v.x + v.y + v.z + v.w; }
  lsum[m] = s;
}

// ---------------- 2-phase double-buffered GEMM, tile TM x 128, BK=32 ----------------
// MODE 0: C bf16 [M][N] = (acc + bias[col]) * alpha       (bias may be null)
// MODE 1: C bf16 transposed [N][M] = acc + bias[col]
// MODE 5: C f32 [M][N] = acc / rowsum_in[row] + bias[col]
template <int MODE, int TM, int OCC>
__global__ __launch_bounds__(256, OCC) void gemm2p_kernel(
    const unsigned short* __restrict__ A, const unsigned short* __restrict__ BT,
    const float* __restrict__ bias, const float* __restrict__ rowsum_in,
    void* __restrict__ Cout, int M, int N, int K, float alpha) {
  constexpr int MFR = TM / 32;       // m-frags per wave
  constexpr int WROW = TM / 2;       // rows per wm-group
  constexpr int ASZ = TM * 32;       // A elems per buffer
  constexpr int BSZ = 128 * 32;      // B elems per buffer
  __shared__ unsigned short lds[2 * ASZ + 2 * BSZ];

  const int tid = threadIdx.x;
  const int lane = tid & 63, wid = tid >> 6;
  const int hq = lane >> 4, lq = lane & 15;
  const int wm = wid >> 1, wn = wid & 1;

  const int gx = gridDim.x;
  const int nwg = gx * gridDim.y;
  const int orig = blockIdx.y * gx + blockIdx.x;
  const int swz = (orig & 7) * (nwg >> 3) + (orig >> 3);
  const int bx = swz % gx, by = swz / gx;
  const int brow = by * TM, bcol = bx * 128;

  const unsigned short* ap = A + (size_t)(brow + (tid >> 2)) * K + (tid & 3) * 8;
  const unsigned short* bp = BT + (size_t)(bcol + (tid >> 2)) * K + (tid & 3) * 8;
  const size_t row64 = (size_t)64 * K;

  const int nt = K >> 5;
#pragma unroll
  for (int j = 0; j < TM / 64; ++j)
    gload16(ap + j * row64, lds + wid * 512 + j * 2048);
  gload16(bp, lds + 2 * ASZ + wid * 512);
  gload16(bp + row64, lds + 2 * ASZ + wid * 512 + 2048);
  __syncthreads();

  f32x4 acc[MFR][4] = {};
  for (int t = 0; t < nt; ++t) {
    const int cur = t & 1;
    if (t + 1 < nt) {
      const int k0 = (t + 1) * 32;
      unsigned short* an = lds + (cur ^ 1) * ASZ + wid * 512;
      unsigned short* bn = lds + 2 * ASZ + (cur ^ 1) * BSZ + wid * 512;
#pragma unroll
      for (int j = 0; j < TM / 64; ++j)
        gload16(ap + k0 + j * row64, an + j * 2048);
      gload16(bp + k0, bn);
      gload16(bp + k0 + row64, bn + 2048);
    }
    const unsigned short* as0 = lds + cur * ASZ;
    const unsigned short* bs0 = lds + 2 * ASZ + cur * BSZ;
    short8 af[MFR], bfv[4];
#pragma unroll
    for (int mf = 0; mf < MFR; ++mf)
      af[mf] = *reinterpret_cast<const short8*>(&as0[(wm * WROW + mf * 16 + lq) * 32 + hq * 8]);
#pragma unroll
    for (int nf = 0; nf < 4; ++nf)
      bfv[nf] = *reinterpret_cast<const short8*>(&bs0[(wn * 64 + nf * 16 + lq) * 32 + hq * 8]);
#pragma unroll
    for (int mf = 0; mf < MFR; ++mf)
#pragma unroll
      for (int nf = 0; nf < 4; ++nf)
        acc[mf][nf] = MFMA16(af[mf], bfv[nf], acc[mf][nf]);
    if (t + 1 < nt) __syncthreads();
  }

  if (MODE == 5) {
#pragma unroll
    for (int mf = 0; mf < MFR; ++mf)
#pragma unroll
      for (int i = 0; i < 4; ++i) {
        const int rowg = brow + wm * WROW + mf * 16 + hq * 4 + i;
        const float inv = 1.0f / rowsum_in[rowg];
#pragma unroll
        for (int nf = 0; nf < 4; ++nf) {
          const int colg = bcol + wn * 64 + nf * 16 + lq;
          ((float*)Cout)[(size_t)rowg * N + colg] = acc[mf][nf][i] * inv + bias[colg];
        }
      }
  } else if (MODE == 1) {
#pragma unroll
    for (int nf = 0; nf < 4; ++nf) {
      const int colg = bcol + wn * 64 + nf * 16 + lq;
      const float bv = bias ? bias[colg] : 0.f;
#pragma unroll
      for (int mf = 0; mf < MFR; ++mf) {
        const int rowg0 = brow + wm * WROW + mf * 16 + hq * 4;
        ushort4 pk;
        pk.x = f2bf(acc[mf][nf][0] + bv);
        pk.y = f2bf(acc[mf][nf][1] + bv);
        pk.z = f2bf(acc[mf][nf][2] + bv);
        pk.w = f2bf(acc[mf][nf][3] + bv);
        *reinterpret_cast<ushort4*>((unsigned short*)Cout + (size_t)colg * M + rowg0) = pk;
      }
    }
  } else {
#pragma unroll
    for (int nf = 0; nf < 4; ++nf) {
      const int colg = bcol + wn * 64 + nf * 16 + lq;
      const float bv = bias ? bias[colg] : 0.f;
#pragma unroll
      for (int mf = 0; mf < MFR; ++mf) {
        const int rowg0 = brow + wm * WROW + mf * 16 + hq * 4;
#pragma unroll
        for (int i = 0; i < 4; ++i)
          ((unsigned short*)Cout)[(size_t)(rowg0 + i) * N + colg] =
              f2bf((acc[mf][nf][i] + bv) * alpha);
      }
    }
  }
}

// ---------------- scores GEMM: 3-buffer rotation, counted vmcnt, raw barriers ----
// C bf16 [M][N] = exp(acc + colbias[col]); per-wave partial row-sums ->
// psum_out[row*64 + bx*2 + wn]; coalesced P store via two 64-row LDS repack passes.
__global__ __launch_bounds__(256, 3) void gemm3b_kernel(
    const unsigned short* __restrict__ A, const unsigned short* __restrict__ BT,
    const float* __restrict__ colbias, float* __restrict__ psum_out,
    unsigned short* __restrict__ Cout, int M, int N, int K) {
  __shared__ unsigned short lds[3 * 8192];  // 3 bufs x (A 4096 | B 4096) elems, 48 KB
  const int tid = threadIdx.x;
  const int lane = tid & 63, wid = tid >> 6;
  const int hq = lane >> 4, lq = lane & 15;
  const int wm = wid >> 1, wn = wid & 1;

  const int gx = gridDim.x;
  const int nwg = gx * gridDim.y;
  const int orig = blockIdx.y * gx + blockIdx.x;
  const int swz = (orig & 7) * (nwg >> 3) + (orig >> 3);
  const int bx = swz % gx, by = swz / gx;
  const int brow = by * 128, bcol = bx * 128;

  const unsigned short* ap = A + (size_t)(brow + (tid >> 2)) * K + (tid & 3) * 8;
  const unsigned short* bp = BT + (size_t)(bcol + (tid >> 2)) * K + (tid & 3) * 8;
  const size_t row64 = (size_t)64 * K;
  const int dst = wid * 512;

  const int nt = K >> 5;  // 16
  // prologue: stage tiles 0,1 into bufs 0,1 (8 loads); wait tile0's 4
#pragma unroll
  for (int tt = 0; tt < 2; ++tt) {
    unsigned short* ab = lds + tt * 8192;
    gload16(ap + tt * 32, ab + dst);
    gload16(ap + tt * 32 + row64, ab + dst + 2048);
    gload16(bp + tt * 32, ab + 4096 + dst);
    gload16(bp + tt * 32 + row64, ab + 4096 + dst + 2048);
  }
  asm volatile("s_waitcnt vmcnt(4)" ::: "memory");
  __builtin_amdgcn_s_barrier();

  f32x4 acc[4][4] = {};
  for (int t = 0; t < nt; ++t) {
    const unsigned short* ab = lds + (t % 3) * 8192;
    if (t + 2 < nt) {  // stage tile t+2 into the buffer read at t-1 (safe: barrier passed)
      const int k0 = (t + 2) * 32;
      unsigned short* nb = lds + ((t + 2) % 3) * 8192;
      gload16(ap + k0, nb + dst);
      gload16(ap + k0 + row64, nb + dst + 2048);
      gload16(bp + k0, nb + 4096 + dst);
      gload16(bp + k0 + row64, nb + 4096 + dst + 2048);
    }
    short8 af[4], bfv[4];
#pragma unroll
    for (int mf = 0; mf < 4; ++mf)
      af[mf] = *reinterpret_cast<const short8*>(&ab[(wm * 64 + mf * 16 + lq) * 32 + hq * 8]);
#pragma unroll
    for (int nf = 0; nf < 4; ++nf)
      bfv[nf] = *reinterpret_cast<const short8*>(&ab[4096 + (wn * 64 + nf * 16 + lq) * 32 + hq * 8]);
    __builtin_amdgcn_s_setprio(1);
#pragma unroll
    for (int mf = 0; mf < 4; ++mf)
#pragma unroll
      for (int nf = 0; nf < 4; ++nf)
        acc[mf][nf] = MFMA16(af[mf], bfv[nf], acc[mf][nf]);
    __builtin_amdgcn_s_setprio(0);
    // counted wait: tile t+1's 4 loads landed; tile t+2's 4 stay in flight
    if (t + 2 < nt) {
      asm volatile("s_waitcnt vmcnt(4)" ::: "memory");
      __builtin_amdgcn_s_barrier();
    } else if (t + 1 < nt) {
      asm volatile("s_waitcnt vmcnt(0)" ::: "memory");
      __builtin_amdgcn_s_barrier();
    }
  }

  // epilogue: exp + partial sums + coalesced store, two 64-row passes
  float cb[4];
#pragma unroll
  for (int nf = 0; nf < 4; ++nf) cb[nf] = colbias[bcol + wn * 64 + nf * 16 + lq];
#pragma unroll
  for (int p = 0; p < 2; ++p) {
    __syncthreads();  // all waves done with staging LDS / previous pass store
    if (wm == p) {
#pragma unroll
      for (int mf = 0; mf < 4; ++mf)
#pragma unroll
        for (int i = 0; i < 4; ++i) {
          const int rl = mf * 16 + hq * 4 + i;  // 0..63 local row
          float s = 0.f;
#pragma unroll
          for (int nf = 0; nf < 4; ++nf) {
            float pv = __expf(acc[mf][nf][i] + cb[nf]);
            s += pv;
            lds[rl * 136 + wn * 64 + nf * 16 + lq] = f2bf(pv);
          }
          s += __shfl_xor(s, 1);
          s += __shfl_xor(s, 2);
          s += __shfl_xor(s, 4);
          s += __shfl_xor(s, 8);
          if (lq == 0) psum_out[(size_t)(brow + p * 64 + rl) * 64 + bx * 2 + wn] = s;
        }
    }
    __syncthreads();
#pragma unroll
    for (int j = 0; j < 4; ++j) {
      const int chunk = j * 256 + tid;
      const int row = chunk >> 4, c = chunk & 15;
      short8 v = *reinterpret_cast<const short8*>(&lds[row * 136 + c * 8]);
      *reinterpret_cast<short8*>(Cout + (size_t)(brow + p * 64 + row) * N + bcol + c * 8) = v;
    }
  }
}

extern "C" void kernel_launch(void* const* d_in, const int* in_sizes, int n_in,
                              void* d_out, int out_size, void* d_ws, size_t ws_size,
                              hipStream_t stream) {
  const float* model = (const float*)d_in[0];
  const float* ctx   = (const float*)d_in[1];
  const float* Wq = (const float*)d_in[2]; const float* bq = (const float*)d_in[3];
  const float* Wk = (const float*)d_in[4]; const float* bk = (const float*)d_in[5];
  const float* Wv = (const float*)d_in[6]; const float* bv = (const float*)d_in[7];
  const float* Wo = (const float*)d_in[8]; const float* bo = (const float*)d_in[9];
  float* out = (float*)d_out;

  char* ws = (char*)d_ws;
  size_t off = 0;
  auto alloc = [&](size_t bytes) -> void* {
    void* p = ws + off;
    off += (bytes + 255) & ~(size_t)255;
    return p;
  };
  unsigned short* model_bf = (unsigned short*)alloc((size_t)MB_T * DD * 2);
  unsigned short* ctx_bf   = (unsigned short*)alloc((size_t)CC * DD * 2);
  unsigned short* Wq_bf = (unsigned short*)alloc((size_t)DD * AA * 2);   // natural [D][A]
  unsigned short* Wk_bf = (unsigned short*)alloc((size_t)DD * AA * 2);   // natural [D][A]
  unsigned short* Wv_bf = (unsigned short*)alloc((size_t)DD * AA * 2);   // natural [D][A]
  unsigned short* WoT   = (unsigned short*)alloc((size_t)AA * PP * 2);   // [P][A]
  unsigned short* WkqT_bf = (unsigned short*)alloc((size_t)DD * DD * 2); // [d'][d]
  unsigned short* WvoT_bf = (unsigned short*)alloc((size_t)PP * DD * 2); // [p][d]
  unsigned short* KqT_bf  = (unsigned short*)alloc((size_t)CC * DD * 2); // [C][D]
  unsigned short* W2T_bf  = (unsigned short*)alloc((size_t)PP * CC * 2); // [P][C]
  float* bkq  = (float*)alloc((size_t)DD * 4);
  float* bvo  = (float*)alloc((size_t)PP * 4);
  float* wkbq = (float*)alloc((size_t)DD * 4);
  float* bqk  = (float*)alloc((size_t)CC * 4);
  float* lsp  = (float*)alloc((size_t)MB_T * 64 * 4);  // per-(row, colblock*2+wn) partials
  float* lsum = (float*)alloc((size_t)MB_T * 4);
  unsigned short* P_bf = (unsigned short*)alloc((size_t)MB_T * CC * 2);  // 128 MiB

  const float scale = 0.04419417382415922f;  // 1/sqrt(512)

  cast_bf16_kernel<<<2048, 256, 0, stream>>>(model, model_bf, MB_T * DD / 4);
  cast_bf16_kernel<<<1024, 256, 0, stream>>>(ctx, ctx_bf, CC * DD / 4);
  cast3_kernel<<<dim3(256, 3), 256, 0, stream>>>(Wq, Wk, Wv, Wq_bf, Wk_bf, Wv_bf,
                                                 DD * AA / 4);
  transpose_cast_kernel<<<dim3(16, 16), 256, 0, stream>>>(Wo, WoT, AA, PP);

  // bias folds (3 independent 512-row rowdots in one launch)
  rowdot3_kernel<<<dim3(128, 3), 256, 0, stream>>>(
      Wq_bf, bk, bkq, scale,     // bkq[d'] = s*Wq[d']·bk
      Wk_bf, bq, wkbq, scale,    // wkbq[d] = s*Wk[d]·bq
      WoT, bv, bvo, 1.0f);       // bvo[p]  = Wo[:,p]·bv
  rowdot_kernel<<<CC / 4, 256, 0, stream>>>(ctx_bf, wkbq, bqk, 1.0f);  // bqk[c] = ctx[c]·wkbq

  // WkqT[d'][d] = s * sum_a Wq[d'][a] Wk[d][a]
  gemm2p_kernel<0, 128, 4><<<dim3(4, 4), 256, 0, stream>>>(
      Wq_bf, Wk_bf, nullptr, nullptr, WkqT_bf, DD, DD, AA, scale);
  // WvoT[p][d] = sum_a Wo[a][p] Wv[d][a]
  gemm2p_kernel<0, 128, 4><<<dim3(4, 4), 256, 0, stream>>>(
      WoT, Wv_bf, nullptr, nullptr, WvoT_bf, PP, DD, AA, 1.0f);

  // KqT = ctx @ WkqT^T + bkq -> bf16 [4096][512]
  gemm2p_kernel<0, 128, 4><<<dim3(4, 32), 256, 0, stream>>>(
      ctx_bf, WkqT_bf, bkq, nullptr, KqT_bf, CC, DD, DD, 1.0f);
  // W2T = (ctx @ WvoT^T + bvo)^T -> bf16 [512][4096]
  gemm2p_kernel<1, 128, 4><<<dim3(4, 32), 256, 0, stream>>>(
      ctx_bf, WvoT_bf, bvo, nullptr, W2T_bf, CC, PP, DD, 1.0f);

  // P = exp(model @ KqT^T + bqk[col]) -> bf16 [16384][4096]; partial row sums -> lsp
  gemm3b_kernel<<<dim3(32, 128), 256, 0, stream>>>(
      model_bf, KqT_bf, bqk, lsp, P_bf, MB_T, CC, DD);

  // lsum = reduce(lsp)
  reduce_lsum_kernel<<<MB_T / 256, 256, 0, stream>>>(lsp, lsum);

  // out = P @ W2T^T / lsum + bo -> f32 [16384][512]  (64-row tiles, 1024 blocks)
  gemm2p_kernel<5, 64, 5><<<dim3(4, 256), 256, 0, stream>>>(
      P_bf, W2T_bf, bo, lsum, out, MB_T, PP, CC, 1.0f);
}

// Round 7
// 336.386 us; speedup vs baseline: 1.0981x; 1.0981x over previous
//
#include <hip/hip_runtime.h>

// Problem dims
#define MB_T 16384   // B*T
#define DD   512     // model hidden
#define CC   4096    // context entries
#define AA   512     // attn dim
#define PP   512     // out dim

typedef __attribute__((ext_vector_type(4))) float f32x4;
typedef __attribute__((ext_vector_type(8))) short short8;

#define MFMA16(a, b, c) __builtin_amdgcn_mfma_f32_16x16x32_bf16((a), (b), (c), 0, 0, 0)

__device__ __forceinline__ unsigned short f2bf(float f) {
  union { float f; unsigned int u; } cv; cv.f = f;
  unsigned int u = cv.u;
  return (unsigned short)((u + 0x7FFFu + ((u >> 16) & 1u)) >> 16);
}
__device__ __forceinline__ float bf2f(unsigned short u) {
  union { unsigned int i; float f; } c; c.i = (unsigned int)u << 16; return c.f;
}

// async global->LDS, 16B per lane; lds dest is wave-uniform base (+lane*16 by HW)
__device__ __forceinline__ void gload16(const unsigned short* g, unsigned short* l) {
  __builtin_amdgcn_global_load_lds(
      (const __attribute__((address_space(1))) unsigned int*)g,
      (__attribute__((address_space(3))) unsigned int*)l, 16, 0, 0);
}

// ---------------- cast fp32 -> bf16, x4 vectorized ----------------
__global__ void cast_bf16_kernel(const float* __restrict__ in,
                                 unsigned short* __restrict__ out, int n4) {
  int i = blockIdx.x * blockDim.x + threadIdx.x;
  int stride = gridDim.x * blockDim.x;
  for (; i < n4; i += stride) {
    float4 v = reinterpret_cast<const float4*>(in)[i];
    ushort4 o;
    o.x = f2bf(v.x); o.y = f2bf(v.y); o.z = f2bf(v.z); o.w = f2bf(v.w);
    reinterpret_cast<ushort4*>(out)[i] = o;
  }
}

// three casts in one launch (blockIdx.y selects array)
__global__ void cast3_kernel(const float* __restrict__ i0, const float* __restrict__ i1,
                             const float* __restrict__ i2, unsigned short* __restrict__ o0,
                             unsigned short* __restrict__ o1, unsigned short* __restrict__ o2,
                             int n4) {
  const float* in = blockIdx.y == 0 ? i0 : blockIdx.y == 1 ? i1 : i2;
  unsigned short* out = blockIdx.y == 0 ? o0 : blockIdx.y == 1 ? o1 : o2;
  int i = blockIdx.x * blockDim.x + threadIdx.x;
  if (i < n4) {
    float4 v = reinterpret_cast<const float4*>(in)[i];
    ushort4 o;
    o.x = f2bf(v.x); o.y = f2bf(v.y); o.z = f2bf(v.z); o.w = f2bf(v.w);
    reinterpret_cast<ushort4*>(out)[i] = o;
  }
}

// ---------------- W [rows][cols] f32 -> WT [cols][rows] bf16 ----------------
__global__ __launch_bounds__(256) void transpose_cast_kernel(
    const float* __restrict__ W, unsigned short* __restrict__ WT, int rows, int cols) {
  __shared__ float t_s[32][33];
  int bi = blockIdx.y * 32, bj = blockIdx.x * 32;
  int r = threadIdx.x >> 3, c4 = (threadIdx.x & 7) * 4;
  float4 v = *reinterpret_cast<const float4*>(W + (size_t)(bi + r) * cols + bj + c4);
  t_s[r][c4 + 0] = v.x; t_s[r][c4 + 1] = v.y;
  t_s[r][c4 + 2] = v.z; t_s[r][c4 + 3] = v.w;
  __syncthreads();
  ushort4 o;
  o.x = f2bf(t_s[c4 + 0][r]);
  o.y = f2bf(t_s[c4 + 1][r]);
  o.z = f2bf(t_s[c4 + 2][r]);
  o.w = f2bf(t_s[c4 + 3][r]);
  *reinterpret_cast<ushort4*>(WT + (size_t)(bj + r) * rows + bi + c4) = o;
}

// ---------------- out[r] = scale * dot(mat[r,0:512], vec) ----------------
__device__ __forceinline__ void rowdot_body(const unsigned short* mat, const float* vec,
                                            float* outv, float scale) {
  const int lane = threadIdx.x & 63, wid = threadIdx.x >> 6;
  const int row = blockIdx.x * 4 + wid;
  const unsigned short* kr = mat + (size_t)row * 512 + lane * 8;
  float s = 0.f;
  ushort4 a = *reinterpret_cast<const ushort4*>(kr);
  ushort4 b = *reinterpret_cast<const ushort4*>(kr + 4);
  const float* bqp = vec + lane * 8;
  s += bf2f(a.x) * bqp[0]; s += bf2f(a.y) * bqp[1];
  s += bf2f(a.z) * bqp[2]; s += bf2f(a.w) * bqp[3];
  s += bf2f(b.x) * bqp[4]; s += bf2f(b.y) * bqp[5];
  s += bf2f(b.z) * bqp[6]; s += bf2f(b.w) * bqp[7];
#pragma unroll
  for (int d = 1; d < 64; d <<= 1) s += __shfl_xor(s, d);
  if (lane == 0) outv[row] = s * scale;
}

__global__ __launch_bounds__(256) void rowdot_kernel(
    const unsigned short* __restrict__ mat, const float* __restrict__ vec,
    float* __restrict__ outv, float scale) {
  rowdot_body(mat, vec, outv, scale);
}

__global__ __launch_bounds__(256) void rowdot3_kernel(
    const unsigned short* m0, const float* v0, float* o0, float s0,
    const unsigned short* m1, const float* v1, float* o1, float s1,
    const unsigned short* m2, const float* v2, float* o2, float s2) {
  if (blockIdx.y == 0) rowdot_body(m0, v0, o0, s0);
  else if (blockIdx.y == 1) rowdot_body(m1, v1, o1, s1);
  else rowdot_body(m2, v2, o2, s2);
}

// ---------------- lsum[m] = sum_j lsp[m*64+j] ----------------
__global__ __launch_bounds__(256) void reduce_lsum_kernel(
    const float* __restrict__ lsp, float* __restrict__ lsum) {
  int m = blockIdx.x * blockDim.x + threadIdx.x;
  const float4* p = reinterpret_cast<const float4*>(lsp + (size_t)m * 64);
  float s = 0.f;
#pragma unroll
  for (int j = 0; j < 16; ++j) { float4 v = p[j]; s += v.x + v.y + v.z + v.w; }
  lsum[m] = s;
}

// ---------------- 2-phase double-buffered GEMM, 128x128 (small jobs only) ---------
// MODE 0: C bf16 [M][N] = (acc + bias[col]) * alpha
// MODE 1: C bf16 transposed [N][M] = acc + bias[col]
template <int MODE>
__global__ __launch_bounds__(256, 4) void gemm2p_kernel(
    const unsigned short* __restrict__ A, const unsigned short* __restrict__ BT,
    const float* __restrict__ bias, void* __restrict__ Cout,
    int M, int N, int K, float alpha) {
  __shared__ unsigned short lds[4 * 4096];
  const int tid = threadIdx.x;
  const int lane = tid & 63, wid = tid >> 6;
  const int hq = lane >> 4, lq = lane & 15;
  const int wm = wid >> 1, wn = wid & 1;

  const int gx = gridDim.x;
  const int nwg = gx * gridDim.y;
  const int orig = blockIdx.y * gx + blockIdx.x;
  const int swz = (orig & 7) * (nwg >> 3) + (orig >> 3);
  const int bx = swz % gx, by = swz / gx;
  const int brow = by * 128, bcol = bx * 128;

  const unsigned short* ap = A + (size_t)(brow + (tid >> 2)) * K + (tid & 3) * 8;
  const unsigned short* bp = BT + (size_t)(bcol + (tid >> 2)) * K + (tid & 3) * 8;
  const size_t row64 = (size_t)64 * K;

  const int nt = K >> 5;
  gload16(ap, lds + wid * 512);
  gload16(ap + row64, lds + wid * 512 + 2048);
  gload16(bp, lds + 8192 + wid * 512);
  gload16(bp + row64, lds + 8192 + wid * 512 + 2048);
  __syncthreads();

  f32x4 acc[4][4] = {};
  for (int t = 0; t < nt; ++t) {
    const int cur = t & 1;
    if (t + 1 < nt) {
      const int k0 = (t + 1) * 32;
      unsigned short* an = lds + (cur ^ 1) * 4096 + wid * 512;
      unsigned short* bn = lds + 8192 + (cur ^ 1) * 4096 + wid * 512;
      gload16(ap + k0, an);
      gload16(ap + k0 + row64, an + 2048);
      gload16(bp + k0, bn);
      gload16(bp + k0 + row64, bn + 2048);
    }
    const unsigned short* as0 = lds + cur * 4096;
    const unsigned short* bs0 = lds + 8192 + cur * 4096;
    short8 af[4], bfv[4];
#pragma unroll
    for (int mf = 0; mf < 4; ++mf)
      af[mf] = *reinterpret_cast<const short8*>(&as0[(wm * 64 + mf * 16 + lq) * 32 + hq * 8]);
#pragma unroll
    for (int nf = 0; nf < 4; ++nf)
      bfv[nf] = *reinterpret_cast<const short8*>(&bs0[(wn * 64 + nf * 16 + lq) * 32 + hq * 8]);
#pragma unroll
    for (int mf = 0; mf < 4; ++mf)
#pragma unroll
      for (int nf = 0; nf < 4; ++nf)
        acc[mf][nf] = MFMA16(af[mf], bfv[nf], acc[mf][nf]);
    if (t + 1 < nt) __syncthreads();
  }

  if (MODE == 1) {
#pragma unroll
    for (int nf = 0; nf < 4; ++nf) {
      const int colg = bcol + wn * 64 + nf * 16 + lq;
      const float bv = bias ? bias[colg] : 0.f;
#pragma unroll
      for (int mf = 0; mf < 4; ++mf) {
        const int rowg0 = brow + wm * 64 + mf * 16 + hq * 4;
        ushort4 pk;
        pk.x = f2bf(acc[mf][nf][0] + bv);
        pk.y = f2bf(acc[mf][nf][1] + bv);
        pk.z = f2bf(acc[mf][nf][2] + bv);
        pk.w = f2bf(acc[mf][nf][3] + bv);
        *reinterpret_cast<ushort4*>((unsigned short*)Cout + (size_t)colg * M + rowg0) = pk;
      }
    }
  } else {
#pragma unroll
    for (int nf = 0; nf < 4; ++nf) {
      const int colg = bcol + wn * 64 + nf * 16 + lq;
      const float bv = bias ? bias[colg] : 0.f;
#pragma unroll
      for (int mf = 0; mf < 4; ++mf) {
        const int rowg0 = brow + wm * 64 + mf * 16 + hq * 4;
#pragma unroll
        for (int i = 0; i < 4; ++i)
          ((unsigned short*)Cout)[(size_t)(rowg0 + i) * N + colg] =
              f2bf((acc[mf][nf][i] + bv) * alpha);
      }
    }
  }
}

// ================== 8-phase-style 256x256 scores GEMM ==================
// 512 threads (8 waves: 2M x 4N), BK=32, 4 LDS buffers staged 3 tiles ahead,
// counted vmcnt(8) boundaries, swizzled LDS (chunk ^= (row>>1)&3, both sides).
// C bf16 [M][N] = exp(acc + colbias[col]); per-wave partial row sums ->
// psum_out[row*64 + bx*4 + wn]; coalesced P store via full-tile LDS repack.
__global__ __launch_bounds__(512, 1) void gemm8p_scores_kernel(
    const unsigned short* __restrict__ A, const unsigned short* __restrict__ BT,
    const float* __restrict__ colbias, float* __restrict__ psum_out,
    unsigned short* __restrict__ Cout, int M, int N, int K) {
  // staging: 4 bufs x (A 8192 | B 8192) elems = 65536; repack: 256 x 264 = 67584
  __shared__ unsigned short lds[67584];
  const int tid = threadIdx.x;
  const int lane = tid & 63, wid = tid >> 6;
  const int hq = lane >> 4, lq = lane & 15;
  const int wm = wid >> 2, wn = wid & 3;  // 2M x 4N

  const int gx = gridDim.x;                       // 16
  const int nwg = gx * gridDim.y;
  const int orig = blockIdx.y * gx + blockIdx.x;
  const int swz = (orig & 7) * (nwg >> 3) + (orig >> 3);
  const int bx = swz % gx, by = swz / gx;
  const int brow = by * 256, bcol = bx * 256;

  // stage source: thread t covers LDS row srow=t>>2, phys chunk t&3 within a
  // 128-row line; logical chunk pre-swizzled by the read-side involution.
  const int srow = tid >> 2;                      // 0..127
  const int schunk = (tid & 3) ^ ((tid >> 3) & 3);
  const unsigned short* aS = A + (size_t)(brow + srow) * K + schunk * 8;
  const unsigned short* bS = BT + (size_t)(bcol + srow) * K + schunk * 8;
  const size_t row128 = (size_t)128 * K;
  const int dst = wid * 512;                      // wave-uniform

  const int nt = K >> 5;                          // 16
#define SSTAGE_A(tt) do { const int k0 = (tt) * 32;                         \
    unsigned short* bb = lds + ((tt) & 3) * 16384;                          \
    gload16(aS + k0, bb + dst); gload16(aS + row128 + k0, bb + 4096 + dst); } while (0)
#define SSTAGE_B(tt) do { const int k0 = (tt) * 32;                         \
    unsigned short* bb = lds + ((tt) & 3) * 16384 + 8192;                   \
    gload16(bS + k0, bb + dst); gload16(bS + row128 + k0, bb + 4096 + dst); } while (0)

  // prologue: stage tiles 0,1,2 (12 issues/wave); wait tile0 (8 outstanding)
  SSTAGE_A(0); SSTAGE_B(0);
  SSTAGE_A(1); SSTAGE_B(1);
  SSTAGE_A(2); SSTAGE_B(2);
  asm volatile("s_waitcnt vmcnt(8)" ::: "memory");
  __builtin_amdgcn_s_barrier();

  // swizzled read: row r, logical chunk c -> phys chunk c ^ ((r>>1)&3)
  const int cswz = ((lq >> 1) & 3);  // (row>>1)&3 with row = 16a + lq
  f32x4 acc[8][4] = {};
  for (int t = 0; t < nt; ++t) {
    const unsigned short* ab = lds + (t & 3) * 16384;
    const unsigned short* bb = ab + 8192;
    // ---- phase 0: B frags + A frags mf 0..3; stage A of t+3 ----
    short8 bfv[4], af[4];
#pragma unroll
    for (int nf = 0; nf < 4; ++nf)
      bfv[nf] = *reinterpret_cast<const short8*>(
          &bb[(wn * 64 + nf * 16 + lq) * 32 + (hq ^ cswz) * 8]);
#pragma unroll
    for (int mf = 0; mf < 4; ++mf)
      af[mf] = *reinterpret_cast<const short8*>(
          &ab[(wm * 128 + mf * 16 + lq) * 32 + (hq ^ cswz) * 8]);
    if (t + 3 < nt) SSTAGE_A(t + 3);
    __builtin_amdgcn_s_barrier();
    __builtin_amdgcn_s_setprio(1);
#pragma unroll
    for (int mf = 0; mf < 4; ++mf)
#pragma unroll
      for (int nf = 0; nf < 4; ++nf)
        acc[mf][nf] = MFMA16(af[mf], bfv[nf], acc[mf][nf]);
    __builtin_amdgcn_s_setprio(0);
    __builtin_amdgcn_s_barrier();
    // ---- phase 1: A frags mf 4..7; stage B of t+3 ----
#pragma unroll
    for (int mf = 0; mf < 4; ++mf)
      af[mf] = *reinterpret_cast<const short8*>(
          &ab[(wm * 128 + (mf + 4) * 16 + lq) * 32 + (hq ^ cswz) * 8]);
    if (t + 3 < nt) SSTAGE_B(t + 3);
    __builtin_amdgcn_s_barrier();
    __builtin_amdgcn_s_setprio(1);
#pragma unroll
    for (int mf = 0; mf < 4; ++mf)
#pragma unroll
      for (int nf = 0; nf < 4; ++nf)
        acc[mf + 4][nf] = MFMA16(af[mf], bfv[nf], acc[mf + 4][nf]);
    __builtin_amdgcn_s_setprio(0);
    // ---- boundary: counted wait for tile t+1; t+2/t+3 stay in flight ----
    if (t + 3 < nt)      asm volatile("s_waitcnt vmcnt(8)" ::: "memory");
    else if (t + 2 < nt) asm volatile("s_waitcnt vmcnt(4)" ::: "memory");
    else if (t + 1 < nt) asm volatile("s_waitcnt vmcnt(0)" ::: "memory");
    __builtin_amdgcn_s_barrier();
  }
#undef SSTAGE_A
#undef SSTAGE_B

  // epilogue: exp + per-wave partial row sums + repack through LDS
  float cb[4];
#pragma unroll
  for (int nf = 0; nf < 4; ++nf) cb[nf] = colbias[bcol + wn * 64 + nf * 16 + lq];
#pragma unroll
  for (int mf = 0; mf < 8; ++mf)
#pragma unroll
    for (int i = 0; i < 4; ++i) {
      const int rowl = wm * 128 + mf * 16 + hq * 4 + i;
      float s = 0.f;
#pragma unroll
      for (int nf = 0; nf < 4; ++nf) {
        float pv = __expf(acc[mf][nf][i] + cb[nf]);
        s += pv;
        lds[rowl * 264 + wn * 64 + nf * 16 + lq] = f2bf(pv);
      }
      s += __shfl_xor(s, 1);
      s += __shfl_xor(s, 2);
      s += __shfl_xor(s, 4);
      s += __shfl_xor(s, 8);
      if (lq == 0) psum_out[(size_t)(brow + rowl) * 64 + bx * 4 + wn] = s;
    }
  __syncthreads();
  // coalesced P store: 256 rows x 32 chunks of 16B = 8192 chunks, 16 per thread
#pragma unroll
  for (int j = 0; j < 16; ++j) {
    const int c = j * 512 + tid;
    const int row = c >> 5, ch = c & 31;
    short8 v = *reinterpret_cast<const short8*>(&lds[row * 264 + ch * 8]);
    *reinterpret_cast<short8*>(Cout + (size_t)(brow + row) * N + bcol + ch * 8) = v;
  }
}

// ================== 8-phase-style 256x128 out GEMM ==================
// 512 threads (8 waves: 4M x 2N), BK=32, 4 LDS buffers staged 3 tiles ahead,
// counted vmcnt(6) boundaries, swizzled LDS.
// C f32 [M][N] = acc / rowsum_in[row] + bias[col]
__global__ __launch_bounds__(512, 1) void gemm8p_out_kernel(
    const unsigned short* __restrict__ A, const unsigned short* __restrict__ BT,
    const float* __restrict__ bias, const float* __restrict__ rowsum_in,
    float* __restrict__ Cout, int M, int N, int K) {
  __shared__ unsigned short lds[4 * 12288];  // 4 bufs x (A 8192 | B 4096), 96 KB
  const int tid = threadIdx.x;
  const int lane = tid & 63, wid = tid >> 6;
  const int hq = lane >> 4, lq = lane & 15;
  const int wm = wid >> 1, wn = wid & 1;  // 4M x 2N

  const int gx = gridDim.x;                       // 4
  const int nwg = gx * gridDim.y;
  const int orig = blockIdx.y * gx + blockIdx.x;
  const int swz = (orig & 7) * (nwg >> 3) + (orig >> 3);
  const int bx = swz % gx, by = swz / gx;
  const int brow = by * 256, bcol = bx * 128;

  const int srow = tid >> 2;                      // 0..127
  const int schunk = (tid & 3) ^ ((tid >> 3) & 3);
  const unsigned short* aS = A + (size_t)(brow + srow) * K + schunk * 8;
  const unsigned short* bS = BT + (size_t)(bcol + srow) * K + schunk * 8;
  const size_t row128 = (size_t)128 * K;
  const int dst = wid * 512;

  const int nt = K >> 5;                          // 128
#define OSTAGE(tt) do { const int k0 = (tt) * 32;                            \
    unsigned short* bb = lds + ((tt) & 3) * 12288;                           \
    gload16(aS + k0, bb + dst); gload16(aS + row128 + k0, bb + 4096 + dst);  \
    gload16(bS + k0, bb + 8192 + dst); } while (0)

  OSTAGE(0); OSTAGE(1); OSTAGE(2);
  asm volatile("s_waitcnt vmcnt(6)" ::: "memory");
  __builtin_amdgcn_s_barrier();

  const int cswz = ((lq >> 1) & 3);
  f32x4 acc[4][4] = {};
  for (int t = 0; t < nt; ++t) {
    const unsigned short* ab = lds + (t & 3) * 12288;
    const unsigned short* bb = ab + 8192;
    short8 af[4], bfv[4];
#pragma unroll
    for (int mf = 0; mf < 4; ++mf)
      af[mf] = *reinterpret_cast<const short8*>(
          &ab[(wm * 64 + mf * 16 + lq) * 32 + (hq ^ cswz) * 8]);
#pragma unroll
    for (int nf = 0; nf < 4; ++nf)
      bfv[nf] = *reinterpret_cast<const short8*>(
          &bb[(wn * 64 + nf * 16 + lq) * 32 + (hq ^ cswz) * 8]);
    if (t + 3 < nt) OSTAGE(t + 3);
    __builtin_amdgcn_s_barrier();
    __builtin_amdgcn_s_setprio(1);
#pragma unroll
    for (int mf = 0; mf < 4; ++mf)
#pragma unroll
      for (int nf = 0; nf < 4; ++nf)
        acc[mf][nf] = MFMA16(af[mf], bfv[nf], acc[mf][nf]);
    __builtin_amdgcn_s_setprio(0);
    if (t + 3 < nt)      asm volatile("s_waitcnt vmcnt(6)" ::: "memory");
    else if (t + 2 < nt) asm volatile("s_waitcnt vmcnt(3)" ::: "memory");
    else if (t + 1 < nt) asm volatile("s_waitcnt vmcnt(0)" ::: "memory");
    __builtin_amdgcn_s_barrier();
  }
#undef OSTAGE

#pragma unroll
  for (int mf = 0; mf < 4; ++mf)
#pragma unroll
    for (int i = 0; i < 4; ++i) {
      const int rowg = brow + wm * 64 + mf * 16 + hq * 4 + i;
      const float inv = 1.0f / rowsum_in[rowg];
#pragma unroll
      for (int nf = 0; nf < 4; ++nf) {
        const int colg = bcol + wn * 64 + nf * 16 + lq;
        Cout[(size_t)rowg * N + colg] = acc[mf][nf][i] * inv + bias[colg];
      }
    }
}

extern "C" void kernel_launch(void* const* d_in, const int* in_sizes, int n_in,
                              void* d_out, int out_size, void* d_ws, size_t ws_size,
                              hipStream_t stream) {
  const float* model = (const float*)d_in[0];
  const float* ctx   = (const float*)d_in[1];
  const float* Wq = (const float*)d_in[2]; const float* bq = (const float*)d_in[3];
  const float* Wk = (const float*)d_in[4]; const float* bk = (const float*)d_in[5];
  const float* Wv = (const float*)d_in[6]; const float* bv = (const float*)d_in[7];
  const float* Wo = (const float*)d_in[8]; const float* bo = (const float*)d_in[9];
  float* out = (float*)d_out;

  char* ws = (char*)d_ws;
  size_t off = 0;
  auto alloc = [&](size_t bytes) -> void* {
    void* p = ws + off;
    off += (bytes + 255) & ~(size_t)255;
    return p;
  };
  unsigned short* model_bf = (unsigned short*)alloc((size_t)MB_T * DD * 2);
  unsigned short* ctx_bf   = (unsigned short*)alloc((size_t)CC * DD * 2);
  unsigned short* Wq_bf = (unsigned short*)alloc((size_t)DD * AA * 2);   // natural [D][A]
  unsigned short* Wk_bf = (unsigned short*)alloc((size_t)DD * AA * 2);
  unsigned short* Wv_bf = (unsigned short*)alloc((size_t)DD * AA * 2);
  unsigned short* WoT   = (unsigned short*)alloc((size_t)AA * PP * 2);   // [P][A]
  unsigned short* WkqT_bf = (unsigned short*)alloc((size_t)DD * DD * 2); // [d'][d]
  unsigned short* WvoT_bf = (unsigned short*)alloc((size_t)PP * DD * 2); // [p][d]
  unsigned short* KqT_bf  = (unsigned short*)alloc((size_t)CC * DD * 2); // [C][D]
  unsigned short* W2T_bf  = (unsigned short*)alloc((size_t)PP * CC * 2); // [P][C]
  float* bkq  = (float*)alloc((size_t)DD * 4);
  float* bvo  = (float*)alloc((size_t)PP * 4);
  float* wkbq = (float*)alloc((size_t)DD * 4);
  float* bqk  = (float*)alloc((size_t)CC * 4);
  float* lsp  = (float*)alloc((size_t)MB_T * 64 * 4);
  float* lsum = (float*)alloc((size_t)MB_T * 4);
  unsigned short* P_bf = (unsigned short*)alloc((size_t)MB_T * CC * 2);  // 128 MiB

  const float scale = 0.04419417382415922f;  // 1/sqrt(512)

  cast_bf16_kernel<<<2048, 256, 0, stream>>>(model, model_bf, MB_T * DD / 4);
  cast_bf16_kernel<<<1024, 256, 0, stream>>>(ctx, ctx_bf, CC * DD / 4);
  cast3_kernel<<<dim3(256, 3), 256, 0, stream>>>(Wq, Wk, Wv, Wq_bf, Wk_bf, Wv_bf,
                                                 DD * AA / 4);
  transpose_cast_kernel<<<dim3(16, 16), 256, 0, stream>>>(Wo, WoT, AA, PP);

  // bias folds
  rowdot3_kernel<<<dim3(128, 3), 256, 0, stream>>>(
      Wq_bf, bk, bkq, scale,     // bkq[d'] = s*Wq[d']·bk
      Wk_bf, bq, wkbq, scale,    // wkbq[d] = s*Wk[d]·bq
      WoT, bv, bvo, 1.0f);       // bvo[p]  = Wo[:,p]·bv
  rowdot_kernel<<<CC / 4, 256, 0, stream>>>(ctx_bf, wkbq, bqk, 1.0f);  // bqk[c] = ctx[c]·wkbq

  // WkqT[d'][d] = s * sum_a Wq[d'][a] Wk[d][a]
  gemm2p_kernel<0><<<dim3(4, 4), 256, 0, stream>>>(
      Wq_bf, Wk_bf, nullptr, WkqT_bf, DD, DD, AA, scale);
  // WvoT[p][d] = sum_a Wo[a][p] Wv[d][a]
  gemm2p_kernel<0><<<dim3(4, 4), 256, 0, stream>>>(
      WoT, Wv_bf, nullptr, WvoT_bf, PP, DD, AA, 1.0f);

  // KqT = ctx @ WkqT^T + bkq -> bf16 [4096][512]
  gemm2p_kernel<0><<<dim3(4, 32), 256, 0, stream>>>(
      ctx_bf, WkqT_bf, bkq, KqT_bf, CC, DD, DD, 1.0f);
  // W2T = (ctx @ WvoT^T + bvo)^T -> bf16 [512][4096]
  gemm2p_kernel<1><<<dim3(4, 32), 256, 0, stream>>>(
      ctx_bf, WvoT_bf, bvo, W2T_bf, CC, PP, DD, 1.0f);

  // P = exp(model @ KqT^T + bqk[col]) -> bf16 [16384][4096]; partials -> lsp
  gemm8p_scores_kernel<<<dim3(16, 64), 512, 0, stream>>>(
      model_bf, KqT_bf, bqk, lsp, P_bf, MB_T, CC, DD);

  // lsum = reduce(lsp)
  reduce_lsum_kernel<<<MB_T / 256, 256, 0, stream>>>(lsp, lsum);

  // out = P @ W2T^T / lsum + bo -> f32 [16384][512]
  gemm8p_out_kernel<<<dim3(4, 64), 512, 0, stream>>>(
      P_bf, W2T_bf, bo, lsum, out, MB_T, PP, CC);
}